// Round 17
// baseline (508.026 us; speedup 1.0000x reference)
//
#include <hip/hip_runtime.h>
#include <hip/hip_bf16.h>

#define NV    512           // N nodes
#define BN    1024          // B*N rows
#define NNB   30            // neighbors
#define DIM   64
#define HEADS 8
#define DH    128
#define INNER 1024          // HEADS*DH

// jax.nn.gelu approximate=True via sigmoid identity:
// 0.5x(1+tanh(y)) == x * sigmoid(2y), y = 0.79788456(x + 0.044715 x^3)
__device__ __forceinline__ float gelu_t(float x){
    float x3 = x*x*x;
    float a = -1.5957691216057308f*(x + 0.044715f*x3);
    return x / (1.0f + __expf(a));
}
__device__ __forceinline__ unsigned short f2bf(float x){
    __hip_bfloat16 h = __float2bfloat16(x);           // RNE
    return __builtin_bit_cast(unsigned short, h);
}
__device__ __forceinline__ float bflo(unsigned u){ return __uint_as_float(u << 16); }
__device__ __forceinline__ float bfhi(unsigned u){ return __uint_as_float(u & 0xffff0000u); }

// ---------------------------------------------------------------- fused head
// blocks 0..383: LN1 + qkv GEMM (64 rows x 128 cols). layer 0: embed inline; l>=1: read hn.
// blocks 384..639: top-k 30 (one wave per row).
__global__ __launch_bounds__(256) void k_head(const float* __restrict__ hn,   // LN'd h (l>=1)
                                              const float* __restrict__ g,
                                              const float* __restrict__ be,
                                              const float* __restrict__ w,     // (64,3072)
                                              float* __restrict__ qf,
                                              unsigned short* __restrict__ kvh,
                                              const float* __restrict__ coors,
                                              int* __restrict__ idx,
                                              const float* __restrict__ feats, // non-null => layer 0
                                              const float* __restrict__ fe_w,
                                              const float* __restrict__ fe_b,
                                              float* __restrict__ hout){
    __shared__ float At[64][68];
    __shared__ float Wt[64][132];
    int t = threadIdx.x;
    int wv = t >> 6, lane = t & 63;

    if (blockIdx.x < 384){
        int rt = blockIdx.x / 24, ct = blockIdx.x % 24;
        int row0 = rt*64, col0 = ct*128;

        if (feats){
            // layer 0: embed inline (identical FMA order to original), then LN1
            float gk = g[lane], bk = be[lane];
            float fb = fe_b[lane];
            float w0 = fe_w[0*DIM+lane], w1 = fe_w[1*DIM+lane], w2 = fe_w[2*DIM+lane];
            float w3 = fe_w[3*DIM+lane], w4 = fe_w[4*DIM+lane], w5 = fe_w[5*DIM+lane];
            #pragma unroll 4
            for (int rr = 0; rr < 16; rr++){
                int r = wv*16 + rr;
                int row = row0 + r;
                float f0 = feats[row*3+0], f1 = feats[row*3+1], f2 = feats[row*3+2];
                float hv = fb;
                hv += sinf(f0)*w0; hv += sinf(f1)*w1; hv += sinf(f2)*w2;
                hv += cosf(f0)*w3; hv += cosf(f1)*w4; hv += cosf(f2)*w5;
                hv = fmaxf(hv, 0.0f);
                if (ct == 0) hout[(size_t)row*DIM + lane] = hv;
                float s = hv;
                #pragma unroll
                for (int m = 32; m >= 1; m >>= 1) s += __shfl_xor(s, m, 64);
                float mu = s*(1.0f/64.0f);
                float d = hv - mu;
                float vv = d*d;
                #pragma unroll
                for (int m = 32; m >= 1; m >>= 1) vv += __shfl_xor(vv, m, 64);
                At[lane][r] = d / sqrtf(vv*(1.0f/64.0f) + 1e-5f) * gk + bk;
            }
        } else {
            #pragma unroll 4
            for (int rr = 0; rr < 16; rr++){
                int r = wv*16 + rr;
                At[lane][r] = hn[(size_t)(row0+r)*DIM + lane];
            }
        }
        const float* wg = w + col0;
        #pragma unroll
        for (int i = t*4; i < 64*128; i += 1024){
            int k = i >> 7, c = i & 127;
            *(float4*)&Wt[k][c] = *(const float4*)&wg[k*3072 + c];
        }
        __syncthreads();

        int ty = t >> 4, tx = t & 15;
        float acc[4][8];
        #pragma unroll
        for (int i = 0; i < 4; i++)
            #pragma unroll
            for (int j = 0; j < 8; j++) acc[i][j] = 0.0f;

        #pragma unroll 2
        for (int k = 0; k < 64; k++){
            float4 a  = *(const float4*)&At[k][ty*4];
            float4 w0 = *(const float4*)&Wt[k][tx*4];
            float4 w1 = *(const float4*)&Wt[k][64 + tx*4];
            float av[4]  = {a.x, a.y, a.z, a.w};
            float wv8[8] = {w0.x, w0.y, w0.z, w0.w, w1.x, w1.y, w1.z, w1.w};
            #pragma unroll
            for (int i = 0; i < 4; i++)
                #pragma unroll
                for (int j = 0; j < 8; j++) acc[i][j] += av[i]*wv8[j];
        }

        if (ct < 8){
            #pragma unroll
            for (int i = 0; i < 4; i++){
                int r = row0 + ty*4 + i;
                float* dst = &qf[(size_t)r*INNER + col0];
                *(float4*)&dst[tx*4]      = make_float4(acc[i][0], acc[i][1], acc[i][2], acc[i][3]);
                *(float4*)&dst[64 + tx*4] = make_float4(acc[i][4], acc[i][5], acc[i][6], acc[i][7]);
            }
        } else {
            int kvcol0 = col0 - 1024;
            #pragma unroll
            for (int i = 0; i < 4; i++){
                int r = row0 + ty*4 + i;
                unsigned short* dst = &kvh[(size_t)r*2048 + kvcol0];
                ushort4 p0 = { f2bf(acc[i][0]), f2bf(acc[i][1]), f2bf(acc[i][2]), f2bf(acc[i][3]) };
                ushort4 p1 = { f2bf(acc[i][4]), f2bf(acc[i][5]), f2bf(acc[i][6]), f2bf(acc[i][7]) };
                *(ushort4*)&dst[tx*4]      = p0;
                *(ushort4*)&dst[64 + tx*4] = p1;
            }
        }
    } else {
        int row = (blockIdx.x - 384)*4 + wv;
        int b = row >> 9;
        const float* cbp = coors + (size_t)b*NV*3;
        float cx = coors[row*3+0], cy = coors[row*3+1], cz = coors[row*3+2];
        float d2[8];
        int jb = lane*8;
        #pragma unroll
        for (int u = 0; u < 8; u++){
            float dx = cx - cbp[(jb+u)*3+0];
            float dy = cy - cbp[(jb+u)*3+1];
            float dz = cz - cbp[(jb+u)*3+2];
            d2[u] = dx*dx + dy*dy + dz*dz;
        }
        for (int sel = 0; sel < NNB; sel++){
            float bv = d2[0]; int bu = 0;
            #pragma unroll
            for (int u = 1; u < 8; u++) if (d2[u] < bv){ bv = d2[u]; bu = u; }
            int bj = jb + bu;
            #pragma unroll
            for (int m = 32; m >= 1; m >>= 1){
                float ov = __shfl_xor(bv, m, 64);
                int   oj = __shfl_xor(bj, m, 64);
                if (ov < bv || (ov == bv && oj < bj)){ bv = ov; bj = oj; }
            }
            if (lane == 0) idx[row*NNB + sel] = bj;
            #pragma unroll
            for (int u = 0; u < 8; u++) if (jb + u == bj) d2[u] = 1e30f;
        }
    }
}

// ---------------------------------------------------------------- full layer: 1 row per 512-thread block, grid 1024.
// All LDS reads vectorized to b128 (LDS issue pipe is the measured wall).
__global__ __launch_bounds__(512, 8) void k_layer(const float* __restrict__ qf,
                                                const unsigned short* __restrict__ kvh,
                                                const int*   __restrict__ idx,
                                                const float* __restrict__ cin,
                                                float*       __restrict__ cout,
                                                const float* __restrict__ edges,
                                                float* __restrict__ h,
                                                const float* __restrict__ ew1, const float* __restrict__ eb1,
                                                const float* __restrict__ ew2, const float* __restrict__ eb2,
                                                const float* __restrict__ cw1, const float* __restrict__ cb1,
                                                const float* __restrict__ cw2, const float* __restrict__ cb2,
                                                const float* __restrict__ c_scale, const float* __restrict__ c_comb,
                                                const float* __restrict__ out_w,  const float* __restrict__ out_b,
                                                const float* __restrict__ g2, const float* __restrict__ b2,
                                                const float* __restrict__ fw1, const float* __restrict__ fb1,
                                                const float* __restrict__ fw2, const float* __restrict__ fb2,
                                                float* __restrict__ hn,           // LN1'd h for next layer (null on last)
                                                const float* __restrict__ g1n, const float* __restrict__ b1n,
                                                const float* __restrict__ cls_w, const float* __restrict__ cls_b,
                                                float* __restrict__ cls_out){
    __shared__ __align__(16) float qk[NNB][8];     // raw logits; later gelu(lg)
    __shared__ __align__(16) float lg[NNB][8];
    __shared__ __align__(16) float t18[NNB][18];
    __shared__ __align__(16) float t64s[NNB][68];  // 272B rows: 16B-aligned
    __shared__ __align__(16) float cwh[NNB][8];
    __shared__ __align__(16) float attnT[HEADS][32]; // transposed: row = head
    __shared__ float ej[NNB];
    __shared__ float reln[NNB][3];
    __shared__ int   jid[NNB];
    __shared__ __align__(16) float As[INNER];
    __shared__ float red[256];
    __shared__ float hsr[DIM];
    __shared__ __align__(16) float ys[DIM];
    __shared__ __align__(16) float us[256];

    int t = threadIdx.x;
    int wv = t >> 6, lane = t & 63;
    int row = blockIdx.x;
    int b = row >> 9, i = row & (NV-1);

    if (t < NNB) jid[t] = idx[row*NNB + t];
    __syncthreads();

    // q in registers: lane owns dims [lane*16, lane*16+16)
    float qreg[16];
    {
        const float4* qp = (const float4*)&qf[(size_t)row*INNER + lane*16];
        #pragma unroll
        for (int e = 0; e < 4; e++){
            float4 v = qp[e];
            qreg[e*4+0] = v.x; qreg[e*4+1] = v.y; qreg[e*4+2] = v.z; qreg[e*4+3] = v.w;
        }
    }

    if (t < NNB){
        int jj = jid[t];
        ej[t] = edges[(size_t)(b*NV+i)*NV + jj];
        float rx = cin[(b*NV+i)*3+0] - cin[(b*NV+jj)*3+0];
        float ry = cin[(b*NV+i)*3+1] - cin[(b*NV+jj)*3+1];
        float rz = cin[(b*NV+i)*3+2] - cin[(b*NV+jj)*3+2];
        float s = rx*rx + ry*ry + rz*rz;
        float den = fmaxf(sqrtf(s == 0.0f ? 1.0f : s), 1e-8f);
        float cs = c_scale[0];
        reln[t][0] = rx/den*cs;
        reln[t][1] = ry/den*cs;
        reln[t][2] = rz/den*cs;
    }

    // ---- qk logits: 8 waves, wave handles j = wv, wv+8, ...
    int part = lane & 7, hh = lane >> 3;
    #pragma unroll 2
    for (int j = wv; j < NNB; j += 8){
        int jj = jid[j];
        const uint4* kp = (const uint4*)&kvh[(size_t)(b*NV+jj)*2048 + lane*16];
        uint4 u0 = kp[0];
        uint4 u1 = kp[1];
        float acc = qreg[0]*bflo(u0.x) + qreg[1]*bfhi(u0.x)
                  + qreg[2]*bflo(u0.y) + qreg[3]*bfhi(u0.y)
                  + qreg[4]*bflo(u0.z) + qreg[5]*bfhi(u0.z)
                  + qreg[6]*bflo(u0.w) + qreg[7]*bfhi(u0.w);
        acc += qreg[8]*bflo(u1.x)  + qreg[9]*bfhi(u1.x)
             + qreg[10]*bflo(u1.y) + qreg[11]*bfhi(u1.y)
             + qreg[12]*bflo(u1.z) + qreg[13]*bfhi(u1.z)
             + qreg[14]*bflo(u1.w) + qreg[15]*bfhi(u1.w);
        acc += __shfl_xor(acc, 1, 64);
        acc += __shfl_xor(acc, 2, 64);
        acc += __shfl_xor(acc, 4, 64);
        if (part == 0) qk[j][hh] = acc * 0.08838834764831845f;  // 1/sqrt(128)
    }
    __syncthreads();

    // ---- edge MLP layer 1: (qk||e) (9) -> 18, gelu (vectorized qk reads)
    for (int id = t; id < NNB*18; id += 512){
        int j = id/18, u = id%18;
        float4 q0 = *(const float4*)&qk[j][0];
        float4 q1 = *(const float4*)&qk[j][4];
        float acc = eb1[u];
        acc += q0.x*ew1[0*18+u]; acc += q0.y*ew1[1*18+u];
        acc += q0.z*ew1[2*18+u]; acc += q0.w*ew1[3*18+u];
        acc += q1.x*ew1[4*18+u]; acc += q1.y*ew1[5*18+u];
        acc += q1.z*ew1[6*18+u]; acc += q1.w*ew1[7*18+u];
        acc += ej[j]*ew1[8*18+u];
        t18[j][u] = gelu_t(acc);
    }
    __syncthreads();
    // ---- edge MLP layer 2: 18 -> 8; also write gelu(lg) into qk
    if (t < NNB*HEADS){
        int j = t/HEADS, h2 = t%HEADS;
        float acc = eb2[h2];
        #pragma unroll
        for (int k = 0; k < 18; k++) acc += t18[j][k]*ew2[k*HEADS+h2];
        lg[j][h2] = acc;
        qk[j][h2] = gelu_t(acc);
    }
    __syncthreads();

    // ---- coord MLP layer 1: gelu(lg) (8) -> 64, gelu (vectorized qk reads)
    for (int id = t; id < NNB*64; id += 512){
        int j = id/64, u = id%64;
        float4 q0 = *(const float4*)&qk[j][0];
        float4 q1 = *(const float4*)&qk[j][4];
        float acc = cb1[u];
        acc += q0.x*cw1[0*64+u]; acc += q0.y*cw1[1*64+u];
        acc += q0.z*cw1[2*64+u]; acc += q0.w*cw1[3*64+u];
        acc += q1.x*cw1[4*64+u]; acc += q1.y*cw1[5*64+u];
        acc += q1.z*cw1[6*64+u]; acc += q1.w*cw1[7*64+u];
        t64s[j][u] = gelu_t(acc);
    }
    __syncthreads();
    // ---- coord MLP layer 2 (t<240, vectorized t64s) || softmax -> attnT (t in [256,320))
    if (t < NNB*HEADS){
        int j = t/HEADS, h2 = t%HEADS;
        float acc = cb2[h2];
        #pragma unroll
        for (int k4 = 0; k4 < 16; k4++){
            float4 v = *(const float4*)&t64s[j][k4*4];
            acc += v.x*cw2[(k4*4+0)*HEADS+h2];
            acc += v.y*cw2[(k4*4+1)*HEADS+h2];
            acc += v.z*cw2[(k4*4+2)*HEADS+h2];
            acc += v.w*cw2[(k4*4+3)*HEADS+h2];
        }
        cwh[j][h2] = acc;
    }
    if (t >= 256 && t < 320){
        int h2 = (t-256) >> 3, sub = t & 7;   // 8 lanes per head
        float v0 = lg[sub][h2];
        float v1 = lg[sub+8][h2];
        float v2 = lg[sub+16][h2];
        float v3 = (sub < 6) ? lg[sub+24][h2] : -1e30f;
        float m = fmaxf(fmaxf(v0,v1), fmaxf(v2,v3));
        m = fmaxf(m, __shfl_xor(m, 1, 64));
        m = fmaxf(m, __shfl_xor(m, 2, 64));
        m = fmaxf(m, __shfl_xor(m, 4, 64));
        float p0 = expf(v0-m), p1 = expf(v1-m), p2 = expf(v2-m);
        float p3 = (sub < 6) ? expf(v3-m) : 0.0f;
        float l = p0+p1+p2+p3;
        l += __shfl_xor(l, 1, 64);
        l += __shfl_xor(l, 2, 64);
        l += __shfl_xor(l, 4, 64);
        float rl = 1.0f/l;
        attnT[h2][sub]    = p0*rl;
        attnT[h2][sub+8]  = p1*rl;
        attnT[h2][sub+16] = p2*rl;
        if (sub < 6) attnT[h2][sub+24] = p3*rl;
    }
    __syncthreads();

    // ---- coordinate update (t<3) || attn @ V (all threads, attnT float4 reads)
    if (t < 3){
        float acc = 0.0f;
        for (int j = 0; j < NNB; j++){
            float w = 0.0f;
            #pragma unroll
            for (int h2 = 0; h2 < HEADS; h2++) w += cwh[j][h2]*c_comb[h2];
            acc += w*reln[j][t];
        }
        cout[(b*NV+i)*3+t] = cin[(b*NV+i)*3+t] + acc;
    }
    {
        int hv = t >> 6;
        const unsigned short* vb = kvh + (size_t)b*NV*2048 + 1024 + t*2;
        float ax = 0.f, ay = 0.f;
        #pragma unroll
        for (int j4 = 0; j4 < 7; j4++){
            float4 a = *(const float4*)&attnT[hv][j4*4];
            unsigned v0 = *(const unsigned*)(vb + (size_t)jid[j4*4+0]*2048);
            ax += a.x*bflo(v0); ay += a.x*bfhi(v0);
            unsigned v1 = *(const unsigned*)(vb + (size_t)jid[j4*4+1]*2048);
            ax += a.y*bflo(v1); ay += a.y*bfhi(v1);
            unsigned v2 = *(const unsigned*)(vb + (size_t)jid[j4*4+2]*2048);
            ax += a.z*bflo(v2); ay += a.z*bfhi(v2);
            unsigned v3 = *(const unsigned*)(vb + (size_t)jid[j4*4+3]*2048);
            ax += a.w*bflo(v3); ay += a.w*bfhi(v3);
        }
        float2 at = *(const float2*)&attnT[hv][28];
        unsigned v0 = *(const unsigned*)(vb + (size_t)jid[28]*2048);
        ax += at.x*bflo(v0); ay += at.x*bfhi(v0);
        unsigned v1 = *(const unsigned*)(vb + (size_t)jid[29]*2048);
        ax += at.y*bflo(v1); ay += at.y*bfhi(v1);
        *(float2*)&As[t*2] = make_float2(ax, ay);
    }
    __syncthreads();

    // ================= tail on t<256 (4-partial structure; As reads vectorized) ====
    int d = t & 63, prt = (t & 255) >> 6;
    if (t < 256){
        float acc = 0.0f;
        const float* as = &As[prt*256];
        const float* wp = &out_w[(size_t)prt*256*DIM + d];
        #pragma unroll 4
        for (int k4 = 0; k4 < 64; k4++){
            float4 a4 = *(const float4*)&as[k4*4];
            acc += a4.x*wp[(k4*4+0)*DIM];
            acc += a4.y*wp[(k4*4+1)*DIM];
            acc += a4.z*wp[(k4*4+2)*DIM];
            acc += a4.w*wp[(k4*4+3)*DIM];
        }
        red[t] = acc;
    }
    __syncthreads();
    if (t < 64){
        float r = red[t] + red[t+64] + red[t+128] + red[t+192];
        float v = h[(size_t)row*DIM + t] + r + out_b[t];
        hsr[t] = v;
        float s = v;
        #pragma unroll
        for (int m = 32; m >= 1; m >>= 1) s += __shfl_xor(s, m, 64);
        float mu = s*(1.0f/64.0f);
        float dd = v - mu;
        float vv = dd*dd;
        #pragma unroll
        for (int m = 32; m >= 1; m >>= 1) vv += __shfl_xor(vv, m, 64);
        ys[t] = dd / sqrtf(vv*(1.0f/64.0f) + 1e-5f) * g2[t] + b2[t];
    }
    __syncthreads();

    if (t < 256){
        float u = fb1[t];
        #pragma unroll 4
        for (int k4 = 0; k4 < 16; k4++){
            float4 y4 = *(const float4*)&ys[k4*4];
            u += y4.x*fw1[(k4*4+0)*256 + t];
            u += y4.y*fw1[(k4*4+1)*256 + t];
            u += y4.z*fw1[(k4*4+2)*256 + t];
            u += y4.w*fw1[(k4*4+3)*256 + t];
        }
        us[t] = gelu_t(u);
    }
    __syncthreads();

    if (t < 256){
        float f2 = 0.0f;
        const float* up = &us[prt*64];
        const float* wp2 = &fw2[(size_t)prt*64*DIM + d];
        #pragma unroll 4
        for (int k4 = 0; k4 < 16; k4++){
            float4 u4 = *(const float4*)&up[k4*4];
            f2 += u4.x*wp2[(k4*4+0)*DIM];
            f2 += u4.y*wp2[(k4*4+1)*DIM];
            f2 += u4.z*wp2[(k4*4+2)*DIM];
            f2 += u4.w*wp2[(k4*4+3)*DIM];
        }
        red[t] = f2;
    }
    __syncthreads();
    if (t < 64){
        float f2 = fb2[t] + red[t] + red[t+64] + red[t+128] + red[t+192];
        float hv = hsr[t] + f2;
        h[(size_t)row*DIM + t] = hv;
        if (hn){
            float s = hv;
            #pragma unroll
            for (int m = 32; m >= 1; m >>= 1) s += __shfl_xor(s, m, 64);
            float mu = s*(1.0f/64.0f);
            float dd = hv - mu;
            float vv = dd*dd;
            #pragma unroll
            for (int m = 32; m >= 1; m >>= 1) vv += __shfl_xor(vv, m, 64);
            hn[(size_t)row*DIM + t] = dd / sqrtf(vv*(1.0f/64.0f) + 1e-5f) * g1n[t] + b1n[t];
        }
        if (cls_out) ys[t] = hv;
    }

    // ---- classifier + softmax (last layer only; same FMA order as original)
    if (cls_out){
        __syncthreads();
        if (t < 20){
            float acc = cls_b[t];
            #pragma unroll 8
            for (int k = 0; k < 64; k++) acc += ys[k]*cls_w[k*20+t];
            red[t] = acc;
        }
        __syncthreads();
        if (t < 20){
            float m = -1e30f;
            for (int c = 0; c < 20; c++) m = fmaxf(m, red[c]);
            float l = 0.0f;
            for (int c = 0; c < 20; c++) l += expf(red[c]-m);
            cls_out[row*20+t] = expf(red[t]-m)/l;
        }
    }
}

extern "C" void kernel_launch(void* const* d_in, const int* in_sizes, int n_in,
                              void* d_out, int out_size, void* d_ws, size_t ws_size,
                              hipStream_t stream) {
    const float* feats = (const float*)d_in[0];
    const float* coors = (const float*)d_in[1];
    const float* edges = (const float*)d_in[2];
    // d_in[3] = mask (all true) — unused
    const float* fe_w  = (const float*)d_in[4];
    const float* fe_b  = (const float*)d_in[5];
    const float* ln1_g = (const float*)d_in[6];
    const float* ln1_b = (const float*)d_in[7];
    const float* qkv_w = (const float*)d_in[8];
    const float* out_w = (const float*)d_in[9];
    const float* out_b = (const float*)d_in[10];
    const float* ew1   = (const float*)d_in[11];
    const float* eb1   = (const float*)d_in[12];
    const float* ew2   = (const float*)d_in[13];
    const float* eb2   = (const float*)d_in[14];
    const float* cw1   = (const float*)d_in[15];
    const float* cb1   = (const float*)d_in[16];
    const float* cw2   = (const float*)d_in[17];
    const float* cb2   = (const float*)d_in[18];
    const float* c_scale = (const float*)d_in[19];
    const float* c_comb  = (const float*)d_in[20];
    const float* ln2_g = (const float*)d_in[21];
    const float* ln2_b = (const float*)d_in[22];
    const float* fw1   = (const float*)d_in[23];
    const float* fb1   = (const float*)d_in[24];
    const float* fw2   = (const float*)d_in[25];
    const float* fb2   = (const float*)d_in[26];
    const float* cls_w = (const float*)d_in[27];
    const float* cls_b = (const float*)d_in[28];

    float* ws   = (float*)d_ws;
    float* h    = ws;                                  // 1024*64
    float* hn   = h + BN*DIM;                          // 1024*64 (LN1'd for next layer)
    float* cA   = hn + BN*DIM;                         // 1024*3
    float* cB   = cA + BN*3;                           // 1024*3
    float* qf   = cB + BN*3;                           // 1024*1024 f32 (4 MB): Q
    unsigned short* kvh = (unsigned short*)(qf + (size_t)BN*INNER); // 1024*2048 bf16 (4 MB): K|V
    int*   idx  = (int*)(kvh + (size_t)BN*2048);       // 1024*30

    const float* cin = coors;      // layer 0 reads input coords directly
    float*       cout = cA;
    for (int l = 0; l < 8; l++){
        k_head<<<640, 256, 0, stream>>>(hn, ln1_g + l*DIM, ln1_b + l*DIM,
                                        qkv_w + (size_t)l*DIM*3*INNER,
                                        qf, kvh, cin, idx,
                                        (l == 0) ? feats : nullptr, fe_w, fe_b, h);
        k_layer<<<BN, 512, 0, stream>>>(qf, kvh, idx, cin, cout, edges, h,
                                        ew1 + l*9*18,  eb1 + l*18,
                                        ew2 + l*18*8,  eb2 + l*8,
                                        cw1 + l*8*64,  cb1 + l*64,
                                        cw2 + l*64*8,  cb2 + l*8,
                                        c_scale + l,   c_comb + l*8,
                                        out_w + (size_t)l*INNER*DIM, out_b + l*DIM,
                                        ln2_g + l*DIM, ln2_b + l*DIM,
                                        fw1 + (size_t)l*DIM*256, fb1 + l*256,
                                        fw2 + (size_t)l*256*DIM, fb2 + l*64,
                                        (l < 7) ? hn : nullptr,
                                        ln1_g + (l+1 < 8 ? (l+1)*DIM : 0),
                                        ln1_b + (l+1 < 8 ? (l+1)*DIM : 0),
                                        cls_w, cls_b,
                                        (l == 7) ? (float*)d_out : nullptr);
        cin = cout;
        cout = (cout == cA) ? cB : cA;
    }
}

// Round 18
// 494.277 us; speedup vs baseline: 1.0278x; 1.0278x over previous
//
#include <hip/hip_runtime.h>
#include <hip/hip_bf16.h>

#define NV    512           // N nodes
#define BN    1024          // B*N rows
#define NNB   30            // neighbors
#define DIM   64
#define HEADS 8
#define DH    128
#define INNER 1024          // HEADS*DH

// jax.nn.gelu default: approximate=True (tanh form)
__device__ __forceinline__ float gelu_t(float x){
    float x3 = x*x*x;
    return 0.5f*x*(1.0f + tanhf(0.7978845608028654f*(x + 0.044715f*x3)));
}
__device__ __forceinline__ unsigned short f2bf(float x){
    __hip_bfloat16 h = __float2bfloat16(x);           // RNE
    return __builtin_bit_cast(unsigned short, h);
}
__device__ __forceinline__ float bflo(unsigned u){ return __uint_as_float(u << 16); }
__device__ __forceinline__ float bfhi(unsigned u){ return __uint_as_float(u & 0xffff0000u); }

// ---------------------------------------------------------------- fused head
// blocks 0..383: LN1 + qkv GEMM (64 rows x 128 cols). layer 0: embed inline; l>=1: read hn.
// blocks 384..639: top-k 30 (one wave per row).
__global__ __launch_bounds__(256) void k_head(const float* __restrict__ hn,   // LN'd h (l>=1)
                                              const float* __restrict__ g,
                                              const float* __restrict__ be,
                                              const float* __restrict__ w,     // (64,3072)
                                              float* __restrict__ qf,
                                              unsigned short* __restrict__ kvh,
                                              const float* __restrict__ coors,
                                              int* __restrict__ idx,
                                              const float* __restrict__ feats, // non-null => layer 0
                                              const float* __restrict__ fe_w,
                                              const float* __restrict__ fe_b,
                                              float* __restrict__ hout){
    __shared__ float At[64][68];
    __shared__ float Wt[64][132];
    int t = threadIdx.x;
    int wv = t >> 6, lane = t & 63;

    if (blockIdx.x < 384){
        int rt = blockIdx.x / 24, ct = blockIdx.x % 24;
        int row0 = rt*64, col0 = ct*128;

        if (feats){
            // layer 0: embed inline (identical FMA order to original), then LN1
            float gk = g[lane], bk = be[lane];
            float fb = fe_b[lane];
            float w0 = fe_w[0*DIM+lane], w1 = fe_w[1*DIM+lane], w2 = fe_w[2*DIM+lane];
            float w3 = fe_w[3*DIM+lane], w4 = fe_w[4*DIM+lane], w5 = fe_w[5*DIM+lane];
            #pragma unroll 4
            for (int rr = 0; rr < 16; rr++){
                int r = wv*16 + rr;
                int row = row0 + r;
                float f0 = feats[row*3+0], f1 = feats[row*3+1], f2 = feats[row*3+2];
                float hv = fb;
                hv += sinf(f0)*w0; hv += sinf(f1)*w1; hv += sinf(f2)*w2;
                hv += cosf(f0)*w3; hv += cosf(f1)*w4; hv += cosf(f2)*w5;
                hv = fmaxf(hv, 0.0f);
                if (ct == 0) hout[(size_t)row*DIM + lane] = hv;
                float s = hv;
                #pragma unroll
                for (int m = 32; m >= 1; m >>= 1) s += __shfl_xor(s, m, 64);
                float mu = s*(1.0f/64.0f);
                float d = hv - mu;
                float vv = d*d;
                #pragma unroll
                for (int m = 32; m >= 1; m >>= 1) vv += __shfl_xor(vv, m, 64);
                At[lane][r] = d / sqrtf(vv*(1.0f/64.0f) + 1e-5f) * gk + bk;
            }
        } else {
            // l>=1: hn already LN'd by previous k_layer epilogue
            #pragma unroll 4
            for (int rr = 0; rr < 16; rr++){
                int r = wv*16 + rr;
                At[lane][r] = hn[(size_t)(row0+r)*DIM + lane];
            }
        }
        const float* wg = w + col0;
        #pragma unroll
        for (int i = t*4; i < 64*128; i += 1024){
            int k = i >> 7, c = i & 127;
            *(float4*)&Wt[k][c] = *(const float4*)&wg[k*3072 + c];
        }
        __syncthreads();

        int ty = t >> 4, tx = t & 15;
        float acc[4][8];
        #pragma unroll
        for (int i = 0; i < 4; i++)
            #pragma unroll
            for (int j = 0; j < 8; j++) acc[i][j] = 0.0f;

        #pragma unroll 2
        for (int k = 0; k < 64; k++){
            float4 a  = *(const float4*)&At[k][ty*4];
            float4 w0 = *(const float4*)&Wt[k][tx*4];
            float4 w1 = *(const float4*)&Wt[k][64 + tx*4];
            float av[4]  = {a.x, a.y, a.z, a.w};
            float wv8[8] = {w0.x, w0.y, w0.z, w0.w, w1.x, w1.y, w1.z, w1.w};
            #pragma unroll
            for (int i = 0; i < 4; i++)
                #pragma unroll
                for (int j = 0; j < 8; j++) acc[i][j] += av[i]*wv8[j];
        }

        if (ct < 8){
            #pragma unroll
            for (int i = 0; i < 4; i++){
                int r = row0 + ty*4 + i;
                float* dst = &qf[(size_t)r*INNER + col0];
                *(float4*)&dst[tx*4]      = make_float4(acc[i][0], acc[i][1], acc[i][2], acc[i][3]);
                *(float4*)&dst[64 + tx*4] = make_float4(acc[i][4], acc[i][5], acc[i][6], acc[i][7]);
            }
        } else {
            int kvcol0 = col0 - 1024;
            #pragma unroll
            for (int i = 0; i < 4; i++){
                int r = row0 + ty*4 + i;
                unsigned short* dst = &kvh[(size_t)r*2048 + kvcol0];
                ushort4 p0 = { f2bf(acc[i][0]), f2bf(acc[i][1]), f2bf(acc[i][2]), f2bf(acc[i][3]) };
                ushort4 p1 = { f2bf(acc[i][4]), f2bf(acc[i][5]), f2bf(acc[i][6]), f2bf(acc[i][7]) };
                *(ushort4*)&dst[tx*4]      = p0;
                *(ushort4*)&dst[64 + tx*4] = p1;
            }
        }
    } else {
        int row = (blockIdx.x - 384)*4 + wv;
        int b = row >> 9;
        const float* cbp = coors + (size_t)b*NV*3;
        float cx = coors[row*3+0], cy = coors[row*3+1], cz = coors[row*3+2];
        float d2[8];
        int jb = lane*8;
        #pragma unroll
        for (int u = 0; u < 8; u++){
            float dx = cx - cbp[(jb+u)*3+0];
            float dy = cy - cbp[(jb+u)*3+1];
            float dz = cz - cbp[(jb+u)*3+2];
            d2[u] = dx*dx + dy*dy + dz*dz;
        }
        for (int sel = 0; sel < NNB; sel++){
            float bv = d2[0]; int bu = 0;
            #pragma unroll
            for (int u = 1; u < 8; u++) if (d2[u] < bv){ bv = d2[u]; bu = u; }
            int bj = jb + bu;
            #pragma unroll
            for (int m = 32; m >= 1; m >>= 1){
                float ov = __shfl_xor(bv, m, 64);
                int   oj = __shfl_xor(bj, m, 64);
                if (ov < bv || (ov == bv && oj < bj)){ bv = ov; bj = oj; }
            }
            if (lane == 0) idx[row*NNB + sel] = bj;
            #pragma unroll
            for (int u = 0; u < 8; u++) if (jb + u == bj) d2[u] = 1e30f;
        }
    }
}

// ---------------------------------------------------------------- full layer: 1 row per 512-thread block, grid 1024.
// 8 waves/block x 4 blocks/CU = 32 waves/CU (hardware max TLP).
__global__ __launch_bounds__(512, 8) void k_layer(const float* __restrict__ qf,
                                                const unsigned short* __restrict__ kvh,
                                                const int*   __restrict__ idx,
                                                const float* __restrict__ cin,
                                                float*       __restrict__ cout,
                                                const float* __restrict__ edges,
                                                float* __restrict__ h,
                                                const float* __restrict__ ew1, const float* __restrict__ eb1,
                                                const float* __restrict__ ew2, const float* __restrict__ eb2,
                                                const float* __restrict__ cw1, const float* __restrict__ cb1,
                                                const float* __restrict__ cw2, const float* __restrict__ cb2,
                                                const float* __restrict__ c_scale, const float* __restrict__ c_comb,
                                                const float* __restrict__ out_w,  const float* __restrict__ out_b,
                                                const float* __restrict__ g2, const float* __restrict__ b2,
                                                const float* __restrict__ fw1, const float* __restrict__ fb1,
                                                const float* __restrict__ fw2, const float* __restrict__ fb2,
                                                float* __restrict__ hn,           // LN1'd h for next layer (null on last)
                                                const float* __restrict__ g1n, const float* __restrict__ b1n,
                                                const float* __restrict__ cls_w, const float* __restrict__ cls_b,
                                                float* __restrict__ cls_out){
    __shared__ float qk[NNB][HEADS];   // raw logits; later reused for gelu(lg)
    __shared__ float lg[NNB][HEADS];
    __shared__ float t18[NNB][18];
    __shared__ float t64s[NNB][65];
    __shared__ float cwh[NNB][HEADS];
    __shared__ float attn[NNB][HEADS];
    __shared__ float ej[NNB];
    __shared__ float reln[NNB][3];
    __shared__ float wj[NNB];
    __shared__ int   jid[NNB];
    __shared__ float As[INNER];
    __shared__ float red[256];
    __shared__ float hsr[DIM];
    __shared__ float ys[DIM];
    __shared__ float us[256];

    int t = threadIdx.x;
    int wv = t >> 6, lane = t & 63;
    int row = blockIdx.x;
    int b = row >> 9, i = row & (NV-1);

    if (t < NNB) jid[t] = idx[row*NNB + t];
    __syncthreads();

    // q in registers: lane owns dims [lane*16, lane*16+16) -> head = lane>>3 (same per wave)
    float qreg[16];
    {
        const float4* qp = (const float4*)&qf[(size_t)row*INNER + lane*16];
        #pragma unroll
        for (int e = 0; e < 4; e++){
            float4 v = qp[e];
            qreg[e*4+0] = v.x; qreg[e*4+1] = v.y; qreg[e*4+2] = v.z; qreg[e*4+3] = v.w;
        }
    }

    if (t < NNB){
        int jj = jid[t];
        ej[t] = edges[(size_t)(b*NV+i)*NV + jj];
        float rx = cin[(b*NV+i)*3+0] - cin[(b*NV+jj)*3+0];
        float ry = cin[(b*NV+i)*3+1] - cin[(b*NV+jj)*3+1];
        float rz = cin[(b*NV+i)*3+2] - cin[(b*NV+jj)*3+2];
        float s = rx*rx + ry*ry + rz*rz;
        float den = fmaxf(sqrtf(s == 0.0f ? 1.0f : s), 1e-8f);
        float cs = c_scale[0];
        reln[t][0] = rx/den*cs;
        reln[t][1] = ry/den*cs;
        reln[t][2] = rz/den*cs;
    }

    // ---- qk logits: 8 waves, wave handles j = wv, wv+8, ... (<=4 iters)
    int part = lane & 7, hh = lane >> 3;
    #pragma unroll 2
    for (int j = wv; j < NNB; j += 8){
        int jj = jid[j];
        const uint4* kp = (const uint4*)&kvh[(size_t)(b*NV+jj)*2048 + lane*16];
        uint4 u0 = kp[0];
        uint4 u1 = kp[1];
        float acc = qreg[0]*bflo(u0.x) + qreg[1]*bfhi(u0.x)
                  + qreg[2]*bflo(u0.y) + qreg[3]*bfhi(u0.y)
                  + qreg[4]*bflo(u0.z) + qreg[5]*bfhi(u0.z)
                  + qreg[6]*bflo(u0.w) + qreg[7]*bfhi(u0.w);
        acc += qreg[8]*bflo(u1.x)  + qreg[9]*bfhi(u1.x)
             + qreg[10]*bflo(u1.y) + qreg[11]*bfhi(u1.y)
             + qreg[12]*bflo(u1.z) + qreg[13]*bfhi(u1.z)
             + qreg[14]*bflo(u1.w) + qreg[15]*bfhi(u1.w);
        acc += __shfl_xor(acc, 1, 64);
        acc += __shfl_xor(acc, 2, 64);
        acc += __shfl_xor(acc, 4, 64);
        if (part == 0) qk[j][hh] = acc * 0.08838834764831845f;  // 1/sqrt(128)
    }
    __syncthreads();

    // ---- edge MLP layer 1: (qk||e) (9) -> 18, gelu (540 outputs over 512 threads)
    for (int id = t; id < NNB*18; id += 512){
        int j = id/18, u = id%18;
        float acc = eb1[u];
        #pragma unroll
        for (int k = 0; k < 8; k++) acc += qk[j][k]*ew1[k*18+u];
        acc += ej[j]*ew1[8*18+u];
        t18[j][u] = gelu_t(acc);
    }
    __syncthreads();
    // ---- edge MLP layer 2: 18 -> 8; also write gelu(lg) into qk (dead after MLP1)
    if (t < NNB*HEADS){
        int j = t/HEADS, h2 = t%HEADS;
        float acc = eb2[h2];
        #pragma unroll
        for (int k = 0; k < 18; k++) acc += t18[j][k]*ew2[k*HEADS+h2];
        lg[j][h2] = acc;
        qk[j][h2] = gelu_t(acc);
    }
    __syncthreads();

    // ---- coord MLP: gelu(lg) (8) -> 64 gelu -> 8 (1920 outputs over 512 threads)
    for (int id = t; id < NNB*64; id += 512){
        int j = id/64, u = id%64;
        float acc = cb1[u];
        #pragma unroll
        for (int k = 0; k < 8; k++) acc += qk[j][k]*cw1[k*64+u];
        t64s[j][u] = gelu_t(acc);
    }
    __syncthreads();
    if (t < NNB*HEADS){
        int j = t/HEADS, h2 = t%HEADS;
        float acc = cb2[h2];
        #pragma unroll 8
        for (int k = 0; k < 64; k++) acc += t64s[j][k]*cw2[k*HEADS+h2];
        cwh[j][h2] = acc;
    }
    __syncthreads();

    // ---- per-neighbor coord weight (t<30) | wave-parallel softmax (t in [64,128))
    if (t < NNB){
        float acc = 0.0f;
        #pragma unroll
        for (int h2 = 0; h2 < HEADS; h2++) acc += cwh[t][h2]*c_comb[h2];
        wj[t] = acc;
    }
    if (t >= 64 && t < 128){
        int h2 = (t-64) >> 3, sub = t & 7;   // 8 lanes per head
        float v0 = lg[sub][h2];
        float v1 = lg[sub+8][h2];
        float v2 = lg[sub+16][h2];
        float v3 = (sub < 6) ? lg[sub+24][h2] : -1e30f;
        float m = fmaxf(fmaxf(v0,v1), fmaxf(v2,v3));
        m = fmaxf(m, __shfl_xor(m, 1, 64));
        m = fmaxf(m, __shfl_xor(m, 2, 64));
        m = fmaxf(m, __shfl_xor(m, 4, 64));
        float p0 = expf(v0-m), p1 = expf(v1-m), p2 = expf(v2-m);
        float p3 = (sub < 6) ? expf(v3-m) : 0.0f;
        float l = p0+p1+p2+p3;
        l += __shfl_xor(l, 1, 64);
        l += __shfl_xor(l, 2, 64);
        l += __shfl_xor(l, 4, 64);
        float rl = 1.0f/l;
        attn[sub][h2]    = p0*rl;
        attn[sub+8][h2]  = p1*rl;
        attn[sub+16][h2] = p2*rl;
        if (sub < 6) attn[sub+24][h2] = p3*rl;
    }
    __syncthreads();

    // ---- coordinate update
    if (t < 3){
        float acc = 0.0f;
        for (int j = 0; j < NNB; j++) acc += wj[j]*reln[j][t];
        cout[(b*NV+i)*3+t] = cin[(b*NV+i)*3+t] + acc;
    }

    // ---- attn @ V (bf16): thread owns channels [t*2, t*2+2), head = t>>6
    {
        int hv = t >> 6;
        const unsigned short* vb = kvh + (size_t)b*NV*2048 + 1024 + t*2;
        float ax = 0.f, ay = 0.f;
        for (int j = 0; j < NNB; j++){
            float a = attn[j][hv];
            unsigned v = *(const unsigned*)(vb + (size_t)jid[j]*2048);
            ax += a*bflo(v); ay += a*bfhi(v);
        }
        *(float2*)&As[t*2] = make_float2(ax, ay);
    }
    __syncthreads();

    // ================= tail on t<256 (round-12 structure, FMA order identical) ====
    int d = t & 63, prt = (t & 255) >> 6;
    if (t < 256){
        float acc = 0.0f;
        const float* as = &As[prt*256];
        const float* wp = &out_w[(size_t)prt*256*DIM + d];
        #pragma unroll 8
        for (int k = 0; k < 256; k++) acc += as[k]*wp[k*DIM];
        red[t] = acc;
    }
    __syncthreads();
    if (t < 64){
        float r = red[t] + red[t+64] + red[t+128] + red[t+192];
        float v = h[(size_t)row*DIM + t] + r + out_b[t];
        hsr[t] = v;
        float s = v;
        #pragma unroll
        for (int m = 32; m >= 1; m >>= 1) s += __shfl_xor(s, m, 64);
        float mu = s*(1.0f/64.0f);
        float dd = v - mu;
        float vv = dd*dd;
        #pragma unroll
        for (int m = 32; m >= 1; m >>= 1) vv += __shfl_xor(vv, m, 64);
        ys[t] = dd / sqrtf(vv*(1.0f/64.0f) + 1e-5f) * g2[t] + b2[t];
    }
    __syncthreads();

    if (t < 256){
        float u = fb1[t];
        #pragma unroll 8
        for (int k = 0; k < 64; k++) u += ys[k]*fw1[k*256 + t];
        us[t] = gelu_t(u);
    }
    __syncthreads();

    if (t < 256){
        float f2 = 0.0f;
        const float* up = &us[prt*64];
        const float* wp2 = &fw2[(size_t)prt*64*DIM + d];
        #pragma unroll 8
        for (int k = 0; k < 64; k++) f2 += up[k]*wp2[k*DIM];
        red[t] = f2;
    }
    __syncthreads();
    if (t < 64){
        float f2 = fb2[t] + red[t] + red[t+64] + red[t+128] + red[t+192];
        float hv = hsr[t] + f2;
        h[(size_t)row*DIM + t] = hv;
        if (hn){
            // LN1 for next layer (bitwise-identical tree to k_head's)
            float s = hv;
            #pragma unroll
            for (int m = 32; m >= 1; m >>= 1) s += __shfl_xor(s, m, 64);
            float mu = s*(1.0f/64.0f);
            float dd = hv - mu;
            float vv = dd*dd;
            #pragma unroll
            for (int m = 32; m >= 1; m >>= 1) vv += __shfl_xor(vv, m, 64);
            hn[(size_t)row*DIM + t] = dd / sqrtf(vv*(1.0f/64.0f) + 1e-5f) * g1n[t] + b1n[t];
        }
        if (cls_out) ys[t] = hv;
    }

    // ---- classifier + softmax (last layer only; same FMA order as original)
    if (cls_out){
        __syncthreads();
        if (t < 20){
            float acc = cls_b[t];
            #pragma unroll 8
            for (int k = 0; k < 64; k++) acc += ys[k]*cls_w[k*20+t];
            red[t] = acc;
        }
        __syncthreads();
        if (t < 20){
            float m = -1e30f;
            for (int c = 0; c < 20; c++) m = fmaxf(m, red[c]);
            float l = 0.0f;
            for (int c = 0; c < 20; c++) l += expf(red[c]-m);
            cls_out[row*20+t] = expf(red[t]-m)/l;
        }
    }
}

extern "C" void kernel_launch(void* const* d_in, const int* in_sizes, int n_in,
                              void* d_out, int out_size, void* d_ws, size_t ws_size,
                              hipStream_t stream) {
    const float* feats = (const float*)d_in[0];
    const float* coors = (const float*)d_in[1];
    const float* edges = (const float*)d_in[2];
    // d_in[3] = mask (all true) — unused
    const float* fe_w  = (const float*)d_in[4];
    const float* fe_b  = (const float*)d_in[5];
    const float* ln1_g = (const float*)d_in[6];
    const float* ln1_b = (const float*)d_in[7];
    const float* qkv_w = (const float*)d_in[8];
    const float* out_w = (const float*)d_in[9];
    const float* out_b = (const float*)d_in[10];
    const float* ew1   = (const float*)d_in[11];
    const float* eb1   = (const float*)d_in[12];
    const float* ew2   = (const float*)d_in[13];
    const float* eb2   = (const float*)d_in[14];
    const float* cw1   = (const float*)d_in[15];
    const float* cb1   = (const float*)d_in[16];
    const float* cw2   = (const float*)d_in[17];
    const float* cb2   = (const float*)d_in[18];
    const float* c_scale = (const float*)d_in[19];
    const float* c_comb  = (const float*)d_in[20];
    const float* ln2_g = (const float*)d_in[21];
    const float* ln2_b = (const float*)d_in[22];
    const float* fw1   = (const float*)d_in[23];
    const float* fb1   = (const float*)d_in[24];
    const float* fw2   = (const float*)d_in[25];
    const float* fb2   = (const float*)d_in[26];
    const float* cls_w = (const float*)d_in[27];
    const float* cls_b = (const float*)d_in[28];

    float* ws   = (float*)d_ws;
    float* h    = ws;                                  // 1024*64
    float* hn   = h + BN*DIM;                          // 1024*64 (LN1'd for next layer)
    float* cA   = hn + BN*DIM;                         // 1024*3
    float* cB   = cA + BN*3;                           // 1024*3
    float* qf   = cB + BN*3;                           // 1024*1024 f32 (4 MB): Q
    unsigned short* kvh = (unsigned short*)(qf + (size_t)BN*INNER); // 1024*2048 bf16 (4 MB): K|V
    int*   idx  = (int*)(kvh + (size_t)BN*2048);       // 1024*30

    const float* cin = coors;      // layer 0 reads input coords directly
    float*       cout = cA;
    for (int l = 0; l < 8; l++){
        k_head<<<640, 256, 0, stream>>>(hn, ln1_g + l*DIM, ln1_b + l*DIM,
                                        qkv_w + (size_t)l*DIM*3*INNER,
                                        qf, kvh, cin, idx,
                                        (l == 0) ? feats : nullptr, fe_w, fe_b, h);
        k_layer<<<BN, 512, 0, stream>>>(qf, kvh, idx, cin, cout, edges, h,
                                        ew1 + l*9*18,  eb1 + l*18,
                                        ew2 + l*18*8,  eb2 + l*8,
                                        cw1 + l*8*64,  cb1 + l*64,
                                        cw2 + l*64*8,  cb2 + l*8,
                                        c_scale + l,   c_comb + l*8,
                                        out_w + (size_t)l*INNER*DIM, out_b + l*DIM,
                                        ln2_g + l*DIM, ln2_b + l*DIM,
                                        fw1 + (size_t)l*DIM*256, fb1 + l*256,
                                        fw2 + (size_t)l*256*DIM, fb2 + l*64,
                                        (l < 7) ? hn : nullptr,
                                        ln1_g + (l+1 < 8 ? (l+1)*DIM : 0),
                                        ln1_b + (l+1 < 8 ? (l+1)*DIM : 0),
                                        cls_w, cls_b,
                                        (l == 7) ? (float*)d_out : nullptr);
        cin = cout;
        cout = (cout == cA) ? cB : cA;
    }
}